// Round 1
// baseline (509.643 us; speedup 1.0000x reference)
//
#include <hip/hip_runtime.h>
#include <math.h>

#define H 64
#define W 64
#define C 128
#define NB 8
#define COUT 128
#define HWi 4096

// ---------------- Kernel 1: transpose w_reg [128][1152] -> wT [1152][128] ----------
__global__ void k_transpose(const float* __restrict__ w, float* __restrict__ wT){
    int i = blockIdx.x * 256 + threadIdx.x;
    if (i >= COUT * 1152) return;
    int oc = i / 1152, ck = i - oc * 1152;
    wT[ck * COUT + oc] = w[i];
}

// ---------------- Kernel 2: offset (18ch) + modulator (9ch) 3x3 conv ---------------
// block = 256 threads = 64 pixels x 4 channel-quarters; grid = 512 (one row per block)
__global__ void k_offmod(const float* __restrict__ x,
                         const float* __restrict__ w_off, const float* __restrict__ b_off,
                         const float* __restrict__ w_mod, const float* __restrict__ b_mod,
                         float* __restrict__ off, float* __restrict__ mod){
    __shared__ float s_acc[4 * 27 * 64];
    int tid = threadIdx.x;
    int px = tid & 63, cq = tid >> 6;
    int p0 = blockIdx.x * 64;
    int b = p0 >> 12, ho = (p0 >> 6) & 63;
    int wo = px;

    float acc[27];
    #pragma unroll
    for (int i = 0; i < 27; i++) acc[i] = 0.f;

    const float* xb = x + (size_t)b * C * HWi;
    for (int ci = 0; ci < 32; ci++){
        int c = cq * 32 + ci;
        const float* xc = xb + c * HWi;
        float xv[9];
        #pragma unroll
        for (int ki = 0; ki < 3; ki++){
            int iy = ho - 1 + ki;
            bool vy = (iy >= 0 && iy < H);
            #pragma unroll
            for (int kj = 0; kj < 3; kj++){
                int ix = wo - 1 + kj;
                bool v = vy && (ix >= 0 && ix < W);
                xv[ki * 3 + kj] = v ? xc[iy * W + ix] : 0.f;
            }
        }
        #pragma unroll
        for (int oc = 0; oc < 18; oc++){
            const float* wp = w_off + oc * 1152 + c * 9;
            #pragma unroll
            for (int k = 0; k < 9; k++) acc[oc] = fmaf(wp[k], xv[k], acc[oc]);
        }
        #pragma unroll
        for (int oc = 0; oc < 9; oc++){
            const float* wp = w_mod + oc * 1152 + c * 9;
            #pragma unroll
            for (int k = 0; k < 9; k++) acc[18 + oc] = fmaf(wp[k], xv[k], acc[18 + oc]);
        }
    }
    #pragma unroll
    for (int i = 0; i < 27; i++) s_acc[(cq * 27 + i) * 64 + px] = acc[i];
    __syncthreads();

    for (int o = tid; o < 27 * 64; o += 256){
        int oc = o >> 6, pxl = o & 63;
        float v = s_acc[oc * 64 + pxl] + s_acc[(27 + oc) * 64 + pxl]
                + s_acc[(54 + oc) * 64 + pxl] + s_acc[(81 + oc) * 64 + pxl];
        int sp = ho * W + pxl;
        if (oc < 18){
            off[((size_t)b * 18 + oc) * HWi + sp] = v + b_off[oc];
        } else {
            int j = oc - 18;
            float t = v + b_mod[j];
            mod[((size_t)b * 9 + j) * HWi + sp] = 2.f / (1.f + expf(-t));
        }
    }
}

// ---------------- Kernel 3: deformable conv as tiled implicit GEMM -----------------
// block = 256 threads; tile = 32 pixels (half row) x 128 oc; K=1152 in 16 chunks of 72
__global__ void k_deform(const float* __restrict__ x, const float* __restrict__ off,
                         const float* __restrict__ mod, const float* __restrict__ wT,
                         const float* __restrict__ b_reg, float* __restrict__ y){
    __shared__ float s_ws[72 * 128];     // weight chunk [kk][oc]
    __shared__ float s_p[72 * 32];       // patch chunk  [kk][px]
    __shared__ int   s_a[4][288];        // 4 corner addresses per (k,px)
    __shared__ float s_wt[4][288];       // 4 corner weights (validity*mask*bilinear)

    int tid = threadIdx.x;
    int p0 = blockIdx.x * 32;
    int b = p0 >> 12, ho = (p0 >> 6) & 63, wo0 = p0 & 63;

    // ---- per-(k,pixel) sampling metadata ----
    for (int idx = tid; idx < 288; idx += 256){
        int k = idx >> 5, pxl = idx & 31;
        int sp = ho * W + wo0 + pxl;
        float dy = off[((size_t)b * 18 + 2 * k) * HWi + sp];
        float dx = off[((size_t)b * 18 + 2 * k + 1) * HWi + sp];
        float m  = mod[((size_t)b * 9 + k) * HWi + sp];
        int ki = k / 3, kj = k - ki * 3;
        float py  = (float)(ho - 1 + ki) + dy;
        float pxf = (float)(wo0 + pxl - 1 + kj) + dx;
        float y0f = floorf(py), x0f = floorf(pxf);
        float ly = py - y0f, lx = pxf - x0f;
        int iy0 = (int)y0f, ix0 = (int)x0f;
        int iy1 = iy0 + 1, ix1 = ix0 + 1;
        bool vy0 = (iy0 >= 0 && iy0 < H), vy1 = (iy1 >= 0 && iy1 < H);
        bool vx0 = (ix0 >= 0 && ix0 < W), vx1 = (ix1 >= 0 && ix1 < W);
        int cy0 = min(max(iy0, 0), H - 1), cy1 = min(max(iy1, 0), H - 1);
        int cx0 = min(max(ix0, 0), W - 1), cx1 = min(max(ix1, 0), W - 1);
        s_a[0][idx] = cy0 * W + cx0;  s_a[1][idx] = cy0 * W + cx1;
        s_a[2][idx] = cy1 * W + cx0;  s_a[3][idx] = cy1 * W + cx1;
        s_wt[0][idx] = (vy0 && vx0) ? (1.f - ly) * (1.f - lx) * m : 0.f;
        s_wt[1][idx] = (vy0 && vx1) ? (1.f - ly) * lx * m : 0.f;
        s_wt[2][idx] = (vy1 && vx0) ? ly * (1.f - lx) * m : 0.f;
        s_wt[3][idx] = (vy1 && vx1) ? ly * lx * m : 0.f;
    }

    float acc[4][4];
    #pragma unroll
    for (int i = 0; i < 4; i++)
        #pragma unroll
        for (int j = 0; j < 4; j++) acc[i][j] = 0.f;

    int ocg = tid >> 3, pxg = tid & 7;
    int oc0 = ocg * 4, px0 = pxg * 4;

    for (int cc = 0; cc < 16; cc++){
        __syncthreads();
        // stage weight chunk (contiguous copy, coalesced)
        const float4* wsrc = (const float4*)(wT + cc * 9216);
        float4* wdst = (float4*)s_ws;
        #pragma unroll
        for (int j = 0; j < 9; j++) wdst[tid + j * 256] = wsrc[tid + j * 256];
        // compute sampled+masked patch chunk: 8 channels x 9 taps x 32 px
        #pragma unroll
        for (int i = 0; i < 9; i++){
            int idx2 = i * 256 + tid;
            int c_local = idx2 / 288;
            int rem = idx2 - c_local * 288;
            const float* xc = x + ((size_t)b * C + cc * 8 + c_local) * HWi;
            float v = s_wt[0][rem] * xc[s_a[0][rem]]
                    + s_wt[1][rem] * xc[s_a[1][rem]]
                    + s_wt[2][rem] * xc[s_a[2][rem]]
                    + s_wt[3][rem] * xc[s_a[3][rem]];
            int k = rem >> 5, pxl = rem & 31;
            s_p[(c_local * 9 + k) * 32 + pxl] = v;
        }
        __syncthreads();
        // GEMM accumulate: 4 oc x 4 px per thread
        #pragma unroll 8
        for (int kk = 0; kk < 72; kk++){
            float4 wv = *(const float4*)(s_ws + kk * 128 + oc0);
            float4 pv = *(const float4*)(s_p + kk * 32 + px0);
            acc[0][0] = fmaf(wv.x, pv.x, acc[0][0]);
            acc[0][1] = fmaf(wv.x, pv.y, acc[0][1]);
            acc[0][2] = fmaf(wv.x, pv.z, acc[0][2]);
            acc[0][3] = fmaf(wv.x, pv.w, acc[0][3]);
            acc[1][0] = fmaf(wv.y, pv.x, acc[1][0]);
            acc[1][1] = fmaf(wv.y, pv.y, acc[1][1]);
            acc[1][2] = fmaf(wv.y, pv.z, acc[1][2]);
            acc[1][3] = fmaf(wv.y, pv.w, acc[1][3]);
            acc[2][0] = fmaf(wv.z, pv.x, acc[2][0]);
            acc[2][1] = fmaf(wv.z, pv.y, acc[2][1]);
            acc[2][2] = fmaf(wv.z, pv.z, acc[2][2]);
            acc[2][3] = fmaf(wv.z, pv.w, acc[2][3]);
            acc[3][0] = fmaf(wv.w, pv.x, acc[3][0]);
            acc[3][1] = fmaf(wv.w, pv.y, acc[3][1]);
            acc[3][2] = fmaf(wv.w, pv.z, acc[3][2]);
            acc[3][3] = fmaf(wv.w, pv.w, acc[3][3]);
        }
    }

    #pragma unroll
    for (int i = 0; i < 4; i++){
        int oc = oc0 + i;
        float bias = b_reg[oc];
        float4 r;
        r.x = acc[i][0] + bias; r.y = acc[i][1] + bias;
        r.z = acc[i][2] + bias; r.w = acc[i][3] + bias;
        *(float4*)(y + ((size_t)b * COUT + oc) * HWi + ho * W + wo0 + px0) = r;
    }
}

// ---------------- Kernel 4: per-channel mean / rstd --------------------------------
__global__ void k_stats(const float* __restrict__ y, float* __restrict__ stats){
    int c = blockIdx.x, tid = threadIdx.x;
    float s = 0.f, s2 = 0.f;
    for (int b = 0; b < NB; b++){
        const float* p = y + ((size_t)b * COUT + c) * HWi;
        for (int i = tid; i < HWi; i += 256){
            float v = p[i];
            s += v;
            s2 = fmaf(v, v, s2);
        }
    }
    #pragma unroll
    for (int o = 32; o > 0; o >>= 1){
        s  += __shfl_down(s, o, 64);
        s2 += __shfl_down(s2, o, 64);
    }
    __shared__ float ws[8];
    int wid = tid >> 6, lane = tid & 63;
    if (lane == 0){ ws[wid] = s; ws[4 + wid] = s2; }
    __syncthreads();
    if (tid == 0){
        float S  = ws[0] + ws[1] + ws[2] + ws[3];
        float S2 = ws[4] + ws[5] + ws[6] + ws[7];
        float mean = S * (1.f / 32768.f);
        float var  = S2 * (1.f / 32768.f) - mean * mean;
        stats[c] = mean;
        stats[128 + c] = rsqrtf(var + 1e-5f);
    }
}

// ---------------- Kernel 5: normalize + affine + relu ------------------------------
__global__ void k_apply(const float* __restrict__ y, const float* __restrict__ stats,
                        const float* __restrict__ gamma, const float* __restrict__ beta,
                        float* __restrict__ out){
    int e = blockIdx.x * 256 + threadIdx.x;   // float4 index, 1048576 total
    int c = (e >> 10) & 127;
    float4 v = ((const float4*)y)[e];
    float mu = stats[c], rs = stats[128 + c];
    float g = gamma[c] * rs;
    float bt = beta[c] - mu * g;
    v.x = fmaxf(fmaf(v.x, g, bt), 0.f);
    v.y = fmaxf(fmaf(v.y, g, bt), 0.f);
    v.z = fmaxf(fmaf(v.z, g, bt), 0.f);
    v.w = fmaxf(fmaf(v.w, g, bt), 0.f);
    ((float4*)out)[e] = v;
}

extern "C" void kernel_launch(void* const* d_in, const int* in_sizes, int n_in,
                              void* d_out, int out_size, void* d_ws, size_t ws_size,
                              hipStream_t stream){
    const float* x     = (const float*)d_in[0];
    const float* w_off = (const float*)d_in[1];
    const float* b_off = (const float*)d_in[2];
    const float* w_mod = (const float*)d_in[3];
    const float* b_mod = (const float*)d_in[4];
    const float* w_reg = (const float*)d_in[5];
    const float* b_reg = (const float*)d_in[6];
    const float* gamma = (const float*)d_in[7];
    const float* beta  = (const float*)d_in[8];
    float* ws    = (float*)d_ws;
    float* off   = ws;                 // 8*18*4096   = 589824
    float* mod   = ws + 589824;        // 8*9*4096    = 294912
    float* y     = ws + 884736;        // 8*128*4096  = 4194304
    float* wT    = ws + 5079040;       // 1152*128    = 147456
    float* stats = ws + 5226496;       // 256
    float* out   = (float*)d_out;

    hipLaunchKernelGGL(k_transpose, dim3(576),  dim3(256), 0, stream, w_reg, wT);
    hipLaunchKernelGGL(k_offmod,    dim3(512),  dim3(256), 0, stream, x, w_off, b_off, w_mod, b_mod, off, mod);
    hipLaunchKernelGGL(k_deform,    dim3(1024), dim3(256), 0, stream, x, off, mod, wT, b_reg, y);
    hipLaunchKernelGGL(k_stats,     dim3(128),  dim3(256), 0, stream, y, stats);
    hipLaunchKernelGGL(k_apply,     dim3(4096), dim3(256), 0, stream, y, stats, gamma, beta, out);
}

// Round 2
// 165.981 us; speedup vs baseline: 3.0705x; 3.0705x over previous
//
#include <hip/hip_runtime.h>
#include <math.h>

#define H 64
#define W 64
#define C 128
#define NB 8
#define COUT 128
#define HWi 4096
#define NTOT 32768          // NB*HWi
#define KTOT 1152
#define NKC 36              // KTOT/32

typedef __attribute__((ext_vector_type(8))) short short8;
typedef __attribute__((ext_vector_type(8))) unsigned short ushort8;
typedef __attribute__((ext_vector_type(4))) unsigned short ushort4v;
typedef __attribute__((ext_vector_type(4))) float f32x4;

__device__ __forceinline__ unsigned short f2bf(float f){
    unsigned u = __float_as_uint(f);
    unsigned r = (u + 0x7FFFu + ((u >> 16) & 1u)) >> 16;
    return (unsigned short)r;
}
__device__ __forceinline__ float bf2f(unsigned short u){
    return __uint_as_float(((unsigned)u) << 16);
}
__device__ __forceinline__ void gload16(const void* g, void* l){
    __builtin_amdgcn_global_load_lds((const __attribute__((address_space(1))) unsigned int*)g,
                                     (__attribute__((address_space(3))) unsigned int*)l, 16, 0, 0);
}

// ---------- k_prep: weight fragments (bf16) + combined bias ----------
// wA  [kc][oc128][kk32]  kk = k*128+c
// w27A[kc][m32][kk32]
__global__ void k_prep(const float* __restrict__ w_reg, const float* __restrict__ w_off,
                       const float* __restrict__ w_mod, const float* __restrict__ b_off,
                       const float* __restrict__ b_mod,
                       unsigned short* __restrict__ wA, unsigned short* __restrict__ w27A,
                       float* __restrict__ biasom){
    int i = blockIdx.x * 256 + threadIdx.x;
    if (i < 147456){
        int kc = i >> 12, rem = i & 4095, oc = rem >> 5, kkl = rem & 31;
        int kk = kc * 32 + kkl, k = kk >> 7, c = kk & 127;
        wA[i] = f2bf(w_reg[oc * 1152 + c * 9 + k]);
    } else if (i < 147456 + 36864){
        int j = i - 147456;
        int kc = j >> 10, rem = j & 1023, m = rem >> 5, kkl = rem & 31;
        int kk = kc * 32 + kkl, k = kk >> 7, c = kk & 127;
        float v = 0.f;
        if (m < 18) v = w_off[m * 1152 + c * 9 + k];
        else if (m < 27) v = w_mod[(m - 18) * 1152 + c * 9 + k];
        w27A[j] = f2bf(v);
    } else if (i < 147456 + 36864 + 32){
        int m = i - 147456 - 36864;
        biasom[m] = (m < 18) ? b_off[m] : (m < 27 ? b_mod[m - 18] : 0.f);
    }
}

// ---------- k_xpose: x NCHW fp32 -> zero-padded NHWC bf16 [8][66][66][128] ----------
__global__ void k_xpose(const float* __restrict__ x, unsigned short* __restrict__ xTp){
    int bidx = blockIdx.x;                 // 528 = 8*66
    int b = bidx / 66, hp = bidx - b * 66;
    int tid = threadIdx.x;
    unsigned short* row = xTp + (size_t)(b * 66 + hp) * 66 * 128;
    if (hp == 0 || hp == 65){
        ushort8 z = {0,0,0,0,0,0,0,0};
        for (int i = tid; i < 66 * 128 / 8; i += 256) ((ushort8*)row)[i] = z;
        return;
    }
    int h = hp - 1;
    __shared__ unsigned short s[64 * 136];
    int w = tid & 63, c0 = tid >> 6;
    for (int cc = 0; cc < 128; cc += 4){
        int c = cc + c0;
        s[w * 136 + c] = f2bf(x[(size_t)(b * 128 + c) * HWi + h * 64 + w]);
    }
    __syncthreads();
    if (tid < 32){
        ushort8 z = {0,0,0,0,0,0,0,0};
        int wp = (tid < 16) ? 0 : 65;
        int sg = tid & 15;
        *(ushort8*)(row + wp * 128 + sg * 8) = z;
    }
    for (int it = tid; it < 1024; it += 256){
        int w2 = it >> 4, sg = it & 15;
        *(ushort8*)(row + (w2 + 1) * 128 + sg * 8) = *(const ushort8*)(s + w2 * 136 + sg * 8);
    }
}

// ---------- k_gemm27: offset+mod conv, MFMA, sigmoid fused -> OM[n][32] bf16 ----------
__global__ __launch_bounds__(256) void k_gemm27(const unsigned short* __restrict__ xTp,
        const unsigned short* __restrict__ w27A, const float* __restrict__ biasom,
        unsigned short* __restrict__ OM){
    __shared__ unsigned short sA[32 * 32];
    __shared__ unsigned short sB[64 * 32];
    int tid = threadIdx.x;
    int n0 = blockIdx.x * 64;
    int b = n0 >> 12, h = (n0 >> 6) & 63;
    int wave = tid >> 6, lane = tid & 63, quad = lane >> 4, l16 = lane & 15;
    int nl = tid >> 2, sg = tid & 3;
    f32x4 acc0 = {0.f,0.f,0.f,0.f}, acc1 = {0.f,0.f,0.f,0.f};
    for (int kc = 0; kc < NKC; kc++){
        int k = kc >> 2, cb = (kc & 3) << 5;
        int ki = k / 3, kj = k - ki * 3;
        __syncthreads();
        if (tid < 128) gload16(w27A + kc * 1024 + tid * 8, (char*)sA + tid * 16);
        {
            int rowi = (b * 66 + h + ki) * 66 + (nl + kj);
            gload16(xTp + (size_t)rowi * 128 + cb + sg * 8, (char*)sB + tid * 16);
        }
        __syncthreads();
        short8 bfrag = *(const short8*)(sB + (wave * 16 + l16) * 32 + quad * 8);
        short8 a0 = *(const short8*)(sA + l16 * 32 + quad * 8);
        short8 a1 = *(const short8*)(sA + (16 + l16) * 32 + quad * 8);
        acc0 = __builtin_amdgcn_mfma_f32_16x16x32_bf16(a0, bfrag, acc0, 0, 0, 0);
        acc1 = __builtin_amdgcn_mfma_f32_16x16x32_bf16(a1, bfrag, acc1, 0, 0, 0);
    }
    int n = n0 + wave * 16 + l16;
    #pragma unroll
    for (int t = 0; t < 2; t++){
        f32x4 a = t ? acc1 : acc0;
        ushort4v o;
        #pragma unroll
        for (int r = 0; r < 4; r++){
            int oc = t * 16 + quad * 4 + r;
            float v = a[r] + biasom[oc];
            if (oc >= 18) v = 2.f / (1.f + expf(-v));
            o[r] = f2bf(v);
        }
        *(ushort4v*)(OM + n * 32 + t * 16 + quad * 4) = o;
    }
}

// ---------- k_gemm128: deformable conv, fused bilinear sampling + MFMA ----------
__global__ __launch_bounds__(256, 2) void k_gemm128(const unsigned short* __restrict__ xTp,
        const unsigned short* __restrict__ OM, const unsigned short* __restrict__ wA,
        const float* __restrict__ b_reg, unsigned short* __restrict__ ybf){
    __shared__ int   s_a[4][576];
    __shared__ float s_w[4][576];
    __shared__ unsigned short sA[128 * 32];   // 8 KB
    __shared__ unsigned short sB[64 * 32];    // 4 KB
    int tid = threadIdx.x;
    int n0 = blockIdx.x * 64;
    int b = n0 >> 12, h = (n0 >> 6) & 63;

    for (int idx = tid; idx < 576; idx += 256){
        int k = idx >> 6, px = idx & 63;
        int n = n0 + px;
        float dy = bf2f(OM[n * 32 + 2 * k]);
        float dx = bf2f(OM[n * 32 + 2 * k + 1]);
        float m  = bf2f(OM[n * 32 + 18 + k]);
        int ki = k / 3, kj = k - ki * 3;
        float py  = (float)(h - 1 + ki) + dy;
        float pxf = (float)(px - 1 + kj) + dx;
        float y0f = floorf(py), x0f = floorf(pxf);
        float ly = py - y0f, lx = pxf - x0f;
        int iy0 = (int)y0f, ix0 = (int)x0f;
        int cy0 = min(max(iy0 + 1, 0), 65), cy1 = min(max(iy0 + 2, 0), 65);
        int cx0 = min(max(ix0 + 1, 0), 65), cx1 = min(max(ix0 + 2, 0), 65);
        int rb = b * 66 * 66;
        s_a[0][idx] = ((rb + cy0 * 66) + cx0) * 128;
        s_a[1][idx] = ((rb + cy0 * 66) + cx1) * 128;
        s_a[2][idx] = ((rb + cy1 * 66) + cx0) * 128;
        s_a[3][idx] = ((rb + cy1 * 66) + cx1) * 128;
        s_w[0][idx] = (1.f - ly) * (1.f - lx) * m;
        s_w[1][idx] = (1.f - ly) * lx * m;
        s_w[2][idx] = ly * (1.f - lx) * m;
        s_w[3][idx] = ly * lx * m;
    }

    int wave = tid >> 6, lane = tid & 63, quad = lane >> 4, l16 = lane & 15;
    int ns = tid & 63, cg = tid >> 6;
    f32x4 acc[8];
    #pragma unroll
    for (int t = 0; t < 8; t++) acc[t] = (f32x4){0.f,0.f,0.f,0.f};

    for (int kc = 0; kc < NKC; kc++){
        int k = kc >> 2, cb = (kc & 3) << 5;
        __syncthreads();
        gload16(wA + kc * 4096 + tid * 8,        (char*)sA + tid * 16);
        gload16(wA + kc * 4096 + 2048 + tid * 8, (char*)sA + 4096 + tid * 16);
        {
            int idx = k * 64 + ns;
            int co = cb + cg * 8;
            const unsigned short* p0 = xTp + s_a[0][idx] + co;
            const unsigned short* p1 = xTp + s_a[1][idx] + co;
            const unsigned short* p2 = xTp + s_a[2][idx] + co;
            const unsigned short* p3 = xTp + s_a[3][idx] + co;
            float w0 = s_w[0][idx], w1 = s_w[1][idx], w2 = s_w[2][idx], w3 = s_w[3][idx];
            ushort8 u0 = *(const ushort8*)p0;
            ushort8 u1 = *(const ushort8*)p1;
            ushort8 u2 = *(const ushort8*)p2;
            ushort8 u3 = *(const ushort8*)p3;
            ushort8 o;
            #pragma unroll
            for (int s = 0; s < 8; s++){
                float v = w0 * bf2f(u0[s]) + w1 * bf2f(u1[s])
                        + w2 * bf2f(u2[s]) + w3 * bf2f(u3[s]);
                o[s] = f2bf(v);
            }
            *(ushort8*)(sB + ns * 32 + cg * 8) = o;
        }
        __syncthreads();
        short8 bfrag = *(const short8*)(sB + (wave * 16 + l16) * 32 + quad * 8);
        #pragma unroll
        for (int t = 0; t < 8; t++){
            short8 afrag = *(const short8*)(sA + (t * 16 + l16) * 32 + quad * 8);
            acc[t] = __builtin_amdgcn_mfma_f32_16x16x32_bf16(afrag, bfrag, acc[t], 0, 0, 0);
        }
    }

    int n = n0 + wave * 16 + l16;
    int sp = n & 4095;
    #pragma unroll
    for (int t = 0; t < 8; t++){
        #pragma unroll
        for (int r = 0; r < 4; r++){
            int oc = t * 16 + quad * 4 + r;
            float v = acc[t][r] + b_reg[oc];
            ybf[(size_t)(b * 128 + oc) * HWi + sp] = f2bf(v);
        }
    }
}

// ---------- stats (two-stage, deterministic) ----------
__global__ void k_stats1(const unsigned short* __restrict__ ybf, float* __restrict__ psum){
    int blk = blockIdx.x;            // c*8+b, 1024
    int c = blk >> 3, b = blk & 7;
    const unsigned short* p = ybf + (size_t)(b * 128 + c) * HWi;
    int tid = threadIdx.x;
    float s = 0.f, s2 = 0.f;
    for (int i = tid * 8; i < HWi; i += 2048){
        ushort8 u = *(const ushort8*)(p + i);
        #pragma unroll
        for (int j = 0; j < 8; j++){
            float v = bf2f(u[j]);
            s += v; s2 = fmaf(v, v, s2);
        }
    }
    #pragma unroll
    for (int o = 32; o > 0; o >>= 1){
        s  += __shfl_down(s, o, 64);
        s2 += __shfl_down(s2, o, 64);
    }
    __shared__ float ws[8];
    int wid = tid >> 6, lane = tid & 63;
    if (lane == 0){ ws[wid] = s; ws[4 + wid] = s2; }
    __syncthreads();
    if (tid == 0){
        psum[blk]        = ws[0] + ws[1] + ws[2] + ws[3];
        psum[1024 + blk] = ws[4] + ws[5] + ws[6] + ws[7];
    }
}

__global__ void k_stats2(const float* __restrict__ psum, float* __restrict__ stats){
    int c = threadIdx.x;
    if (c >= 128) return;
    float S = 0.f, S2 = 0.f;
    for (int b = 0; b < 8; b++){ S += psum[c * 8 + b]; S2 += psum[1024 + c * 8 + b]; }
    float mean = S * (1.f / 32768.f);
    float var  = S2 * (1.f / 32768.f) - mean * mean;
    stats[c] = mean;
    stats[128 + c] = rsqrtf(var + 1e-5f);
}

// ---------- apply: normalize + affine + relu -> fp32 out ----------
__global__ void k_apply(const unsigned short* __restrict__ ybf, const float* __restrict__ stats,
                        const float* __restrict__ gamma, const float* __restrict__ beta,
                        float* __restrict__ out){
    int e8 = (blockIdx.x * 256 + threadIdx.x) * 8;   // 4194304 elems total
    int c = (e8 >> 12) & 127;
    ushort8 u = *(const ushort8*)(ybf + e8);
    float mu = stats[c], rs = stats[128 + c];
    float g = gamma[c] * rs;
    float bt = beta[c] - mu * g;
    float4 lo, hi;
    lo.x = fmaxf(fmaf(bf2f(u[0]), g, bt), 0.f);
    lo.y = fmaxf(fmaf(bf2f(u[1]), g, bt), 0.f);
    lo.z = fmaxf(fmaf(bf2f(u[2]), g, bt), 0.f);
    lo.w = fmaxf(fmaf(bf2f(u[3]), g, bt), 0.f);
    hi.x = fmaxf(fmaf(bf2f(u[4]), g, bt), 0.f);
    hi.y = fmaxf(fmaf(bf2f(u[5]), g, bt), 0.f);
    hi.z = fmaxf(fmaf(bf2f(u[6]), g, bt), 0.f);
    hi.w = fmaxf(fmaf(bf2f(u[7]), g, bt), 0.f);
    *(float4*)(out + e8)     = lo;
    *(float4*)(out + e8 + 4) = hi;
}

extern "C" void kernel_launch(void* const* d_in, const int* in_sizes, int n_in,
                              void* d_out, int out_size, void* d_ws, size_t ws_size,
                              hipStream_t stream){
    const float* x     = (const float*)d_in[0];
    const float* w_off = (const float*)d_in[1];
    const float* b_off = (const float*)d_in[2];
    const float* w_mod = (const float*)d_in[3];
    const float* b_mod = (const float*)d_in[4];
    const float* w_reg = (const float*)d_in[5];
    const float* b_reg = (const float*)d_in[6];
    const float* gamma = (const float*)d_in[7];
    const float* beta  = (const float*)d_in[8];

    char* wsb = (char*)d_ws;
    unsigned short* xTp   = (unsigned short*)(wsb);                    // 8,921,088 B
    unsigned short* OM    = (unsigned short*)(wsb + 8921088);          // 2,097,152 B
    unsigned short* ybf   = (unsigned short*)(wsb + 11018240);         // 8,388,608 B
    unsigned short* wA    = (unsigned short*)(wsb + 19406848);         //   294,912 B
    unsigned short* w27A  = (unsigned short*)(wsb + 19701760);         //    73,728 B
    float*          biasom= (float*)(wsb + 19775488);                  //       128 B
    float*          psum  = (float*)(wsb + 19775616);                  //     8,192 B
    float*          stats = (float*)(wsb + 19783808);                  //     1,024 B
    float* out = (float*)d_out;

    hipLaunchKernelGGL(k_prep,   dim3(721),  dim3(256), 0, stream, w_reg, w_off, w_mod, b_off, b_mod, wA, w27A, biasom);
    hipLaunchKernelGGL(k_xpose,  dim3(528),  dim3(256), 0, stream, x, xTp);
    hipLaunchKernelGGL(k_gemm27, dim3(512),  dim3(256), 0, stream, xTp, w27A, biasom, OM);
    hipLaunchKernelGGL(k_gemm128,dim3(512),  dim3(256), 0, stream, xTp, OM, wA, b_reg, ybf);
    hipLaunchKernelGGL(k_stats1, dim3(1024), dim3(256), 0, stream, ybf, psum);
    hipLaunchKernelGGL(k_stats2, dim3(1),    dim3(128), 0, stream, psum, stats);
    hipLaunchKernelGGL(k_apply,  dim3(2048), dim3(256), 0, stream, ybf, stats, gamma, beta, out);
}

// Round 3
// 147.451 us; speedup vs baseline: 3.4564x; 1.1257x over previous
//
#include <hip/hip_runtime.h>
#include <math.h>

#define H 64
#define W 64
#define C 128
#define NB 8
#define COUT 128
#define HWi 4096
#define NKC 36
#define PADu 40          // LDS row pitch in ushorts (80B = 5 superbanks, conflict-free b128)

typedef __attribute__((ext_vector_type(8))) short short8;
typedef __attribute__((ext_vector_type(8))) unsigned short ushort8;
typedef __attribute__((ext_vector_type(4))) unsigned short ushort4v;
typedef __attribute__((ext_vector_type(4))) float f32x4;

__device__ __forceinline__ unsigned short f2bf(float f){
    unsigned u = __float_as_uint(f);
    unsigned r = (u + 0x7FFFu + ((u >> 16) & 1u)) >> 16;
    return (unsigned short)r;
}
__device__ __forceinline__ float bf2f(unsigned short u){
    return __uint_as_float(((unsigned)u) << 16);
}

// ---------- k_pre: fused x-transpose + weight prep + psum zero ----------
// blocks [0,528): x NCHW fp32 -> zero-padded NHWC bf16 [8][66][66][128]
// blocks [528,1250): wAv swizzled [kc][q4][r128][j8], w27A [kc][m32][kk32], biasom, psum=0
__global__ void k_pre(const float* __restrict__ x, unsigned short* __restrict__ xTp,
                      const float* __restrict__ w_reg, const float* __restrict__ w_off,
                      const float* __restrict__ w_mod, const float* __restrict__ b_off,
                      const float* __restrict__ b_mod,
                      unsigned short* __restrict__ wAv, unsigned short* __restrict__ w27A,
                      float* __restrict__ biasom, float* __restrict__ psum){
    int tid = threadIdx.x;
    if (blockIdx.x >= 528){
        int i = (blockIdx.x - 528) * 256 + tid;
        if (i < 147456){
            int kc = i >> 12, rem = i & 4095;
            int q = rem >> 10, r = (rem >> 3) & 127, j = rem & 7;
            int kk = kc * 32 + q * 8 + j, k = kk >> 7, c = kk & 127;
            wAv[i] = f2bf(w_reg[r * 1152 + c * 9 + k]);
        } else if (i < 147456 + 36864){
            int j2 = i - 147456;
            int kc = j2 >> 10, rem = j2 & 1023, m = rem >> 5, kkl = rem & 31;
            int kk = kc * 32 + kkl, k = kk >> 7, c = kk & 127;
            float v = 0.f;
            if (m < 18) v = w_off[m * 1152 + c * 9 + k];
            else if (m < 27) v = w_mod[(m - 18) * 1152 + c * 9 + k];
            w27A[j2] = f2bf(v);
        } else if (i < 147456 + 36864 + 32){
            int m = i - 147456 - 36864;
            biasom[m] = (m < 18) ? b_off[m] : (m < 27 ? b_mod[m - 18] : 0.f);
        } else if (i < 147456 + 36864 + 32 + 256){
            psum[i - 147456 - 36864 - 32] = 0.f;
        }
        return;
    }
    int bidx = blockIdx.x;
    int b = bidx / 66, hp = bidx - b * 66;
    unsigned short* row = xTp + (size_t)(b * 66 + hp) * 66 * 128;
    if (hp == 0 || hp == 65){
        ushort8 z = {0,0,0,0,0,0,0,0};
        for (int i = tid; i < 66 * 128 / 8; i += 256) ((ushort8*)row)[i] = z;
        return;
    }
    int h = hp - 1;
    __shared__ unsigned short s[64 * 136];
    int w = tid & 63, c0 = tid >> 6;
    for (int cc = 0; cc < 128; cc += 4){
        int c = cc + c0;
        s[w * 136 + c] = f2bf(x[(size_t)(b * 128 + c) * HWi + h * 64 + w]);
    }
    __syncthreads();
    if (tid < 32){
        ushort8 z = {0,0,0,0,0,0,0,0};
        int wp = (tid < 16) ? 0 : 65;
        int sg = tid & 15;
        *(ushort8*)(row + wp * 128 + sg * 8) = z;
    }
    for (int it = tid; it < 1024; it += 256){
        int w2 = it >> 4, sg = it & 15;
        *(ushort8*)(row + (w2 + 1) * 128 + sg * 8) = *(const ushort8*)(s + w2 * 136 + sg * 8);
    }
}

// ---------- k_gemm27: offset+mod conv, MFMA, padded LDS, pipelined ----------
__global__ __launch_bounds__(256) void k_gemm27(const unsigned short* __restrict__ xTp,
        const unsigned short* __restrict__ w27A, const float* __restrict__ biasom,
        unsigned short* __restrict__ OM){
    __shared__ unsigned short sA[2][32 * PADu];
    __shared__ unsigned short sB[2][64 * PADu];
    int tid = threadIdx.x;
    int n0 = blockIdx.x * 64;
    int b = n0 >> 12, h = (n0 >> 6) & 63;
    int wv = tid >> 6, lane = tid & 63, quad = lane >> 4, l16 = lane & 15;
    int nl = tid >> 2, sg = tid & 3;
    f32x4 acc0 = {0.f,0.f,0.f,0.f}, acc1 = {0.f,0.f,0.f,0.f};

    ushort8 rA, rB;
    auto loadNext = [&](int kcn){
        int k = kcn >> 2, cb = (kcn & 3) << 5;
        int ki = k / 3, kj = k - ki * 3;
        if (tid < 128) rA = *(const ushort8*)(w27A + kcn * 1024 + tid * 8);
        int rowi = (b * 66 + h + ki) * 66 + (nl + kj);
        rB = *(const ushort8*)(xTp + (size_t)rowi * 128 + cb + sg * 8);
    };
    loadNext(0);
    for (int kc = 0; kc < NKC; kc++){
        int p = kc & 1;
        if (tid < 128) *(ushort8*)(&sA[p][(tid >> 2) * PADu + (tid & 3) * 8]) = rA;
        *(ushort8*)(&sB[p][nl * PADu + sg * 8]) = rB;
        if (kc + 1 < NKC) loadNext(kc + 1);
        __syncthreads();
        short8 bfrag = *(const short8*)(&sB[p][(wv * 16 + l16) * PADu + quad * 8]);
        short8 a0 = *(const short8*)(&sA[p][l16 * PADu + quad * 8]);
        short8 a1 = *(const short8*)(&sA[p][(16 + l16) * PADu + quad * 8]);
        acc0 = __builtin_amdgcn_mfma_f32_16x16x32_bf16(a0, bfrag, acc0, 0, 0, 0);
        acc1 = __builtin_amdgcn_mfma_f32_16x16x32_bf16(a1, bfrag, acc1, 0, 0, 0);
    }
    int n = n0 + wv * 16 + l16;
    #pragma unroll
    for (int t = 0; t < 2; t++){
        f32x4 a = t ? acc1 : acc0;
        ushort4v o;
        #pragma unroll
        for (int r = 0; r < 4; r++){
            int oc = t * 16 + quad * 4 + r;
            float v = a[r] + biasom[oc];
            if (oc >= 18) v = 2.f / (1.f + expf(-v));
            o[r] = f2bf(v);
        }
        *(ushort4v*)(OM + n * 32 + t * 16 + quad * 4) = o;
    }
}

// ---------- k_gemm128: deformable conv, 512 thr, padded LDS, 1 barrier/kc ----------
__global__ __launch_bounds__(512, 4) void k_gemm128(const unsigned short* __restrict__ xTp,
        const unsigned short* __restrict__ OM, const unsigned short* __restrict__ wAv,
        const float* __restrict__ b_reg, unsigned short* __restrict__ ybf,
        float* __restrict__ psum){
    __shared__ char smem[49152];
    unsigned short* sA = (unsigned short*)smem;             // [2][128*40] = 20480 B
    unsigned short* sB = (unsigned short*)(smem + 20480);   // [2][64*40]  = 10240 B
    int*   s_a0 = (int*)(smem + 30720);                     // [4][576]    = 9216 B
    float* s_w0 = (float*)(smem + 39936);                   // [4][576]    = 9216 B

    int tid = threadIdx.x;
    int n0 = blockIdx.x * 64;
    int b = n0 >> 12, h = (n0 >> 6) & 63;

    for (int idx = tid; idx < 576; idx += 512){
        int k = idx >> 6, px = idx & 63;
        int n = n0 + px;
        float dy = bf2f(OM[n * 32 + 2 * k]);
        float dx = bf2f(OM[n * 32 + 2 * k + 1]);
        float m  = bf2f(OM[n * 32 + 18 + k]);
        int ki = k / 3, kj = k - ki * 3;
        float py  = (float)(h - 1 + ki) + dy;
        float pxf = (float)(px - 1 + kj) + dx;
        float y0f = floorf(py), x0f = floorf(pxf);
        float ly = py - y0f, lx = pxf - x0f;
        int iy0 = (int)y0f, ix0 = (int)x0f;
        int cy0 = min(max(iy0 + 1, 0), 65), cy1 = min(max(iy0 + 2, 0), 65);
        int cx0 = min(max(ix0 + 1, 0), 65), cx1 = min(max(ix0 + 2, 0), 65);
        int rb = b * 66 * 66;
        s_a0[0 * 576 + idx] = ((rb + cy0 * 66) + cx0) * 128;
        s_a0[1 * 576 + idx] = ((rb + cy0 * 66) + cx1) * 128;
        s_a0[2 * 576 + idx] = ((rb + cy1 * 66) + cx0) * 128;
        s_a0[3 * 576 + idx] = ((rb + cy1 * 66) + cx1) * 128;
        s_w0[0 * 576 + idx] = (1.f - ly) * (1.f - lx) * m;
        s_w0[1 * 576 + idx] = (1.f - ly) * lx * m;
        s_w0[2 * 576 + idx] = ly * (1.f - lx) * m;
        s_w0[3 * 576 + idx] = ly * lx * m;
    }
    __syncthreads();

    int wv = tid >> 6, lane = tid & 63, quad = lane >> 4, l16 = lane & 15;
    int ocq = wv & 3, ng = wv >> 2;
    int rA = tid & 127, qA = tid >> 7;            // sA staging role
    int spx = (tid & 255) >> 2, scq = tid & 3;    // sampling role (tid<256)
    bool samp = (tid < 256);

    f32x4 acc00 = {0.f,0.f,0.f,0.f}, acc01 = {0.f,0.f,0.f,0.f};
    f32x4 acc10 = {0.f,0.f,0.f,0.f}, acc11 = {0.f,0.f,0.f,0.f};

    ushort8 rW, rc0, rc1, rc2, rc3;
    float w0 = 0.f, w1 = 0.f, w2 = 0.f, w3 = 0.f;

    auto loadNext = [&](int kcn){
        rW = *(const ushort8*)(wAv + kcn * 4096 + tid * 8);
        if (samp){
            int k = kcn >> 2, cb = (kcn & 3) << 5;
            int idx = k * 64 + spx;
            int co = cb + scq * 8;
            w0 = s_w0[0 * 576 + idx]; w1 = s_w0[1 * 576 + idx];
            w2 = s_w0[2 * 576 + idx]; w3 = s_w0[3 * 576 + idx];
            rc0 = *(const ushort8*)(xTp + s_a0[0 * 576 + idx] + co);
            rc1 = *(const ushort8*)(xTp + s_a0[1 * 576 + idx] + co);
            rc2 = *(const ushort8*)(xTp + s_a0[2 * 576 + idx] + co);
            rc3 = *(const ushort8*)(xTp + s_a0[3 * 576 + idx] + co);
        }
    };
    loadNext(0);
    for (int kc = 0; kc < NKC; kc++){
        int p = kc & 1;
        *(ushort8*)(sA + p * 5120 + rA * PADu + qA * 8) = rW;
        if (samp){
            ushort8 o;
            #pragma unroll
            for (int s = 0; s < 8; s++){
                float v = w0 * bf2f(rc0[s]) + w1 * bf2f(rc1[s])
                        + w2 * bf2f(rc2[s]) + w3 * bf2f(rc3[s]);
                o[s] = f2bf(v);
            }
            *(ushort8*)(sB + p * 2560 + spx * PADu + scq * 8) = o;
        }
        if (kc + 1 < NKC) loadNext(kc + 1);
        __syncthreads();
        const unsigned short* A = sA + p * 5120;
        const unsigned short* Bn = sB + p * 2560;
        short8 a0 = *(const short8*)(A + (ocq * 32 + l16) * PADu + quad * 8);
        short8 a1 = *(const short8*)(A + (ocq * 32 + 16 + l16) * PADu + quad * 8);
        short8 b0 = *(const short8*)(Bn + (ng * 32 + l16) * PADu + quad * 8);
        short8 b1 = *(const short8*)(Bn + (ng * 32 + 16 + l16) * PADu + quad * 8);
        acc00 = __builtin_amdgcn_mfma_f32_16x16x32_bf16(a0, b0, acc00, 0, 0, 0);
        acc01 = __builtin_amdgcn_mfma_f32_16x16x32_bf16(a0, b1, acc01, 0, 0, 0);
        acc10 = __builtin_amdgcn_mfma_f32_16x16x32_bf16(a1, b0, acc10, 0, 0, 0);
        acc11 = __builtin_amdgcn_mfma_f32_16x16x32_bf16(a1, b1, acc11, 0, 0, 0);
    }

    __syncthreads();
    float* ls = (float*)smem;   // [128][68] fp32 = 34816 B (overlaps tiles; done with them)
    int sp0 = h * 64;
    #pragma unroll
    for (int to = 0; to < 2; to++){
        #pragma unroll
        for (int tn = 0; tn < 2; tn++){
            f32x4 a = to ? (tn ? acc11 : acc10) : (tn ? acc01 : acc00);
            int nl = ng * 32 + tn * 16 + l16;
            #pragma unroll
            for (int r = 0; r < 4; r++){
                int oc = ocq * 32 + to * 16 + quad * 4 + r;
                float v = a[r] + b_reg[oc];
                ybf[(size_t)(b * 128 + oc) * HWi + sp0 + nl] = f2bf(v);
                ls[oc * 68 + nl] = v;
            }
        }
    }
    __syncthreads();
    if (tid < 128){
        int oc = tid;
        float s = 0.f, s2 = 0.f;
        #pragma unroll 8
        for (int nl = 0; nl < 64; nl++){
            float v = ls[oc * 68 + nl];
            s += v; s2 = fmaf(v, v, s2);
        }
        atomicAdd(&psum[oc], s);
        atomicAdd(&psum[128 + oc], s2);
    }
}

// ---------- k_apply: BN (stats inline from psum) + affine + relu -> fp32 ----------
__global__ void k_apply(const unsigned short* __restrict__ ybf, const float* __restrict__ psum,
                        const float* __restrict__ gamma, const float* __restrict__ beta,
                        float* __restrict__ out){
    int e8 = (blockIdx.x * 256 + threadIdx.x) * 8;
    int c = (e8 >> 12) & 127;
    ushort8 u = *(const ushort8*)(ybf + e8);
    float s = psum[c], s2 = psum[128 + c];
    float mean = s * (1.f / 32768.f);
    float var  = s2 * (1.f / 32768.f) - mean * mean;
    float rs = rsqrtf(var + 1e-5f);
    float g = gamma[c] * rs;
    float bt = beta[c] - mean * g;
    float4 lo, hi;
    lo.x = fmaxf(fmaf(bf2f(u[0]), g, bt), 0.f);
    lo.y = fmaxf(fmaf(bf2f(u[1]), g, bt), 0.f);
    lo.z = fmaxf(fmaf(bf2f(u[2]), g, bt), 0.f);
    lo.w = fmaxf(fmaf(bf2f(u[3]), g, bt), 0.f);
    hi.x = fmaxf(fmaf(bf2f(u[4]), g, bt), 0.f);
    hi.y = fmaxf(fmaf(bf2f(u[5]), g, bt), 0.f);
    hi.z = fmaxf(fmaf(bf2f(u[6]), g, bt), 0.f);
    hi.w = fmaxf(fmaf(bf2f(u[7]), g, bt), 0.f);
    *(float4*)(out + e8)     = lo;
    *(float4*)(out + e8 + 4) = hi;
}

extern "C" void kernel_launch(void* const* d_in, const int* in_sizes, int n_in,
                              void* d_out, int out_size, void* d_ws, size_t ws_size,
                              hipStream_t stream){
    const float* x     = (const float*)d_in[0];
    const float* w_off = (const float*)d_in[1];
    const float* b_off = (const float*)d_in[2];
    const float* w_mod = (const float*)d_in[3];
    const float* b_mod = (const float*)d_in[4];
    const float* w_reg = (const float*)d_in[5];
    const float* b_reg = (const float*)d_in[6];
    const float* gamma = (const float*)d_in[7];
    const float* beta  = (const float*)d_in[8];

    char* wsb = (char*)d_ws;
    unsigned short* xTp   = (unsigned short*)(wsb);                    // 8,921,088 B
    unsigned short* OM    = (unsigned short*)(wsb + 8921088);          // 2,097,152 B
    unsigned short* ybf   = (unsigned short*)(wsb + 11018240);         // 8,388,608 B
    unsigned short* wAv   = (unsigned short*)(wsb + 19406848);         //   294,912 B
    unsigned short* w27A  = (unsigned short*)(wsb + 19701760);         //    73,728 B
    float*          biasom= (float*)(wsb + 19775488);                  //       128 B
    float*          psum  = (float*)(wsb + 19775616);                  //     1,024 B
    float* out = (float*)d_out;

    hipLaunchKernelGGL(k_pre,    dim3(1250), dim3(256), 0, stream, x, xTp, w_reg, w_off, w_mod, b_off, b_mod, wAv, w27A, biasom, psum);
    hipLaunchKernelGGL(k_gemm27, dim3(512),  dim3(256), 0, stream, xTp, w27A, biasom, OM);
    hipLaunchKernelGGL(k_gemm128,dim3(512),  dim3(512), 0, stream, xTp, OM, wAv, b_reg, ybf, psum);
    hipLaunchKernelGGL(k_apply,  dim3(2048), dim3(256), 0, stream, ybf, psum, gamma, beta, out);
}